// Round 7
// baseline (220.313 us; speedup 1.0000x reference)
//
#include <hip/hip_runtime.h>
#include <hip/hip_bf16.h>

typedef __bf16 bf16_t;
typedef __bf16 bf16x8 __attribute__((ext_vector_type(8)));
typedef __bf16 bf16x4 __attribute__((ext_vector_type(4)));
typedef float f32x4 __attribute__((ext_vector_type(4)));

#define FDIM 512
#define BM 64
#define NTHR 512
#define NTILE 4
#define NBLK 512   // 2048 tiles / 4 per block; exactly 2 blocks/CU resident

// Kernel 1: Qt[g][f] = bf16(Q[f][g]) via LDS-tiled transpose (coalesced both sides)
__global__ void qtrans_kernel(const float* __restrict__ Q, bf16_t* __restrict__ Qt) {
    __shared__ float t[32][33];
    int tx = threadIdx.x & 31;
    int ty = threadIdx.x >> 5;
    int f0 = blockIdx.x * 32;
    int g0 = blockIdx.y * 32;
#pragma unroll
    for (int i = 0; i < 4; ++i)
        t[ty + 8 * i][tx] = Q[(size_t)(f0 + ty + 8 * i) * FDIM + g0 + tx];
    __syncthreads();
#pragma unroll
    for (int i = 0; i < 4; ++i)
        Qt[(size_t)(g0 + ty + 8 * i) * FDIM + f0 + tx] = (bf16_t)t[tx][ty + 8 * i];
}

// Kernel 2: out[b] = sum_g (x Q)[b,g] * x[b,g]
// 512 thr = 8 waves, BM=64, 2 blocks/CU, 4 tiles per block.
// While computing tile t, tile t+1 streams global->regs (2 chunks of 8 float4,
// converted to bf16 regs mid-compute), ds_written after the tile barrier:
// HBM streaming overlaps compute instead of serializing with it.
// Wave w owns col-pairs {w,15-w} as 4 sequential 16-col halves (34 K-steps).
__global__ __launch_bounds__(NTHR, 4) void bilinear_kernel(
    const float* __restrict__ x, const bf16_t* __restrict__ Qt,
    float* __restrict__ out)
{
    __shared__ bf16_t xs[BM * FDIM];   // 64 KB, swizzled: e ^= (row&15)<<3
    __shared__ float rsum[8][BM];

    const int tid = threadIdx.x;
    const int w   = tid >> 6;
    const int l   = tid & 63;
    const int col = l & 15;
    const int kg  = l >> 4;

    // ---- prologue: stage tile0 (serial, once) ----
    {
        const float4* xin = (const float4*)(x + (size_t)blockIdx.x * BM * FDIM);
#pragma unroll 1
        for (int it = 0; it < 4; ++it) {
            float4 vv[4];
#pragma unroll
            for (int j = 0; j < 4; ++j) vv[j] = xin[(it * 4 + j) * NTHR + tid];
#pragma unroll
            for (int j = 0; j < 4; ++j) {
                int e = ((it * 4 + j) * NTHR + tid) * 4;
                int row = e >> 9;
                int se = e ^ ((row & 15) << 3);
                bf16x4 b;
                b[0] = (bf16_t)vv[j].x; b[1] = (bf16_t)vv[j].y;
                b[2] = (bf16_t)vv[j].z; b[3] = (bf16_t)vv[j].w;
                *(bf16x4*)(xs + se) = b;
            }
            __builtin_amdgcn_sched_barrier(0);
        }
    }
    __syncthreads();

#pragma unroll 1
    for (int t = 0; t < NTILE; ++t) {
        const size_t blk = ((size_t)t * NBLK + blockIdx.x) * BM;
        const bool pf = (t + 1 < NTILE);
        const float4* xnext = (const float4*)(x + (blk + (size_t)NBLK * BM) * FDIM);

        // issue chunk A loads for next tile (rows 0..31) — overlap with compute
        float4 fA[8];
        if (pf) {
#pragma unroll
            for (int j = 0; j < 8; ++j) fA[j] = xnext[j * NTHR + tid];
        }
        __builtin_amdgcn_sched_barrier(0);

        float rs[4][4];
#pragma unroll
        for (int m = 0; m < 4; ++m)
#pragma unroll
            for (int j = 0; j < 4; ++j) rs[m][j] = 0.0f;

        bf16x4 bA[8], bB[8];

        // ---- compute: 4 half-pair iterations ----
#pragma unroll 1
        for (int pi = 0; pi < 4; ++pi) {
            const int p  = (pi < 2) ? w : (15 - w);
            const int h  = pi & 1;
            const int c0 = p * 32 + h * 16;
            const int nk = p + 1;

            f32x4 acc[4];
#pragma unroll
            for (int m = 0; m < 4; ++m)
#pragma unroll
                for (int j = 0; j < 4; ++j) acc[m][j] = 0.0f;

            const bf16_t* qb = Qt + (size_t)(c0 + col) * FDIM + kg * 8;
            bf16x8 b0 = *(const bf16x8*)(qb);

            for (int ks = 0; ks < nk; ++ks) {
                bf16x8 nb = b0;
                if (ks + 1 < nk) nb = *(const bf16x8*)(qb + (ks + 1) * 32);
                bf16x8 a[4];
#pragma unroll
                for (int m = 0; m < 4; ++m) {
                    int r = m * 16 + col;
                    int e = (r * FDIM + ks * 32 + kg * 8) ^ ((r & 15) << 3);
                    a[m] = *(const bf16x8*)(xs + e);
                }
#pragma unroll
                for (int m = 0; m < 4; ++m)
                    acc[m] = __builtin_amdgcn_mfma_f32_16x16x32_bf16(a[m], b0, acc[m], 0, 0, 0);
                b0 = nb;
            }

#pragma unroll
            for (int m = 0; m < 4; ++m) {
#pragma unroll
                for (int j = 0; j < 4; ++j) {
                    int r = m * 16 + kg * 4 + j;
                    int e = (r * FDIM + c0 + col) ^ ((r & 15) << 3);
                    rs[m][j] += acc[m][j] * (float)xs[e];
                }
            }

            // mid-compute staging transitions
            if (pi == 1 && pf) {
                // chunk A arrived during pi 0-1: convert to bf16, free float4s
#pragma unroll
                for (int j = 0; j < 8; ++j) {
                    bA[j][0] = (bf16_t)fA[j].x; bA[j][1] = (bf16_t)fA[j].y;
                    bA[j][2] = (bf16_t)fA[j].z; bA[j][3] = (bf16_t)fA[j].w;
                }
                // issue chunk B loads (rows 32..63)
#pragma unroll
                for (int j = 0; j < 8; ++j) fA[j] = xnext[(8 + j) * NTHR + tid];
                __builtin_amdgcn_sched_barrier(0);
            }
            if (pi == 3 && pf) {
#pragma unroll
                for (int j = 0; j < 8; ++j) {
                    bB[j][0] = (bf16_t)fA[j].x; bB[j][1] = (bf16_t)fA[j].y;
                    bB[j][2] = (bf16_t)fA[j].z; bB[j][3] = (bf16_t)fA[j].w;
                }
            }
        }

        // ---- reduce across 16 cols (lanes sharing kg) ----
#pragma unroll
        for (int m = 0; m < 4; ++m) {
#pragma unroll
            for (int j = 0; j < 4; ++j) {
                float v2 = rs[m][j];
                v2 += __shfl_xor(v2, 1);
                v2 += __shfl_xor(v2, 2);
                v2 += __shfl_xor(v2, 4);
                v2 += __shfl_xor(v2, 8);
                rs[m][j] = v2;
            }
        }
        if (col == 0) {
#pragma unroll
            for (int m = 0; m < 4; ++m)
#pragma unroll
                for (int j = 0; j < 4; ++j)
                    rsum[w][m * 16 + kg * 4 + j] = rs[m][j];
        }
        __syncthreads();   // xs reads done; rsum published

        if (tid < BM) {
            float s = 0.0f;
#pragma unroll
            for (int ww = 0; ww < 8; ++ww) s += rsum[ww][tid];
            out[blk + tid] = s;
        }

        if (pf) {
            // write next tile into xs (swizzled), then publish
#pragma unroll
            for (int j = 0; j < 8; ++j) {
                int e = (j * NTHR + tid) * 4;
                int row = e >> 9;
                int se = e ^ ((row & 15) << 3);
                *(bf16x4*)(xs + se) = bA[j];
            }
#pragma unroll
            for (int j = 0; j < 8; ++j) {
                int e = ((8 + j) * NTHR + tid) * 4;
                int row = e >> 9;
                int se = e ^ ((row & 15) << 3);
                *(bf16x4*)(xs + se) = bB[j];
            }
            __syncthreads();
        }
    }
}

extern "C" void kernel_launch(void* const* d_in, const int* in_sizes, int n_in,
                              void* d_out, int out_size, void* d_ws, size_t ws_size,
                              hipStream_t stream) {
    const float* x = (const float*)d_in[0];
    const float* Q = (const float*)d_in[1];
    float* out = (float*)d_out;
    bf16_t* Qt = (bf16_t*)d_ws;        // 512*512*2 = 512 KB scratch

    dim3 tgrid(FDIM / 32, FDIM / 32);
    qtrans_kernel<<<tgrid, 256, 0, stream>>>(Q, Qt);
    bilinear_kernel<<<NBLK, NTHR, 0, stream>>>(x, Qt, out);
}

// Round 8
// 112.439 us; speedup vs baseline: 1.9594x; 1.9594x over previous
//
#include <hip/hip_runtime.h>
#include <hip/hip_bf16.h>

typedef __bf16 bf16_t;
typedef __bf16 bf16x8 __attribute__((ext_vector_type(8)));
typedef __bf16 bf16x4 __attribute__((ext_vector_type(4)));
typedef float f32x4 __attribute__((ext_vector_type(4)));

#define FDIM 512
#define BM 64
#define NTHR 512

// Kernel 1: Qt[g][f] = bf16(Q[f][g]) via LDS-tiled transpose (coalesced both sides)
__global__ void qtrans_kernel(const float* __restrict__ Q, bf16_t* __restrict__ Qt) {
    __shared__ float t[32][33];
    int tx = threadIdx.x & 31;
    int ty = threadIdx.x >> 5;
    int f0 = blockIdx.x * 32;
    int g0 = blockIdx.y * 32;
#pragma unroll
    for (int i = 0; i < 4; ++i)
        t[ty + 8 * i][tx] = Q[(size_t)(f0 + ty + 8 * i) * FDIM + g0 + tx];
    __syncthreads();
#pragma unroll
    for (int i = 0; i < 4; ++i)
        Qt[(size_t)(g0 + ty + 8 * i) * FDIM + f0 + tx] = (bf16_t)t[tx][ty + 8 * i];
}

// Kernel 2: out[b] = sum_g (x Q)[b,g] * x[b,g]
// 512 thr = 8 waves, BM=64, 2 blocks/CU. K-OUTERMOST: wave w holds
// accumulators for both its col-pairs {w, 15-w} (2 pairs x 2 halves x 4
// row-tiles = 64 acc regs) and loads each A-fragment ONCE per K-step,
// shared across all active columns -> A-frag ds_reads 136 -> 64 per wave.
// Triangle skip: pair p active only while ks <= p; (w+1)+(16-w)=17 balanced.
__global__ __launch_bounds__(NTHR, 4) void bilinear_kernel(
    const float* __restrict__ x, const bf16_t* __restrict__ Qt,
    float* __restrict__ out)
{
    __shared__ bf16_t xs[BM * FDIM];   // 64 KB, swizzled: e ^= (row&15)<<3
    __shared__ float rsum[8][BM];

    const int tid = threadIdx.x;
    const size_t blk = (size_t)blockIdx.x * BM;
    const float4* xin = (const float4*)(x + blk * FDIM);

    // ---- stage x: 16 float4/thread in 4 batches of 4 (proven no-spill) ----
#pragma unroll 1
    for (int it = 0; it < 4; ++it) {
        float4 vv[4];
#pragma unroll
        for (int j = 0; j < 4; ++j) vv[j] = xin[(it * 4 + j) * NTHR + tid];
#pragma unroll
        for (int j = 0; j < 4; ++j) {
            int e = ((it * 4 + j) * NTHR + tid) * 4;
            int row = e >> 9;
            int se = e ^ ((row & 15) << 3);
            bf16x4 b;
            b[0] = (bf16_t)vv[j].x; b[1] = (bf16_t)vv[j].y;
            b[2] = (bf16_t)vv[j].z; b[3] = (bf16_t)vv[j].w;
            *(bf16x4*)(xs + se) = b;
        }
        __builtin_amdgcn_sched_barrier(0);
    }
    __syncthreads();

    const int w   = tid >> 6;
    const int l   = tid & 63;
    const int col = l & 15;
    const int kg  = l >> 4;

    const int p0 = w;        // active for ks <= w
    const int p1 = 15 - w;   // active for ks <= 15-w

    f32x4 acc[2][2][4];      // [pair][16-col half][row-tile] = 64 regs
#pragma unroll
    for (int pi = 0; pi < 2; ++pi)
#pragma unroll
        for (int h = 0; h < 2; ++h)
#pragma unroll
            for (int m = 0; m < 4; ++m)
#pragma unroll
                for (int j = 0; j < 4; ++j) acc[pi][h][m][j] = 0.0f;

    // B-frag base pointers: Qt[(p*32 + h*16 + col)][kg*8 + ks*32 ...]
    const bf16_t* qp[2][2];
#pragma unroll
    for (int pi = 0; pi < 2; ++pi) {
        int p = pi ? p1 : p0;
#pragma unroll
        for (int h = 0; h < 2; ++h)
            qp[pi][h] = Qt + (size_t)(p * 32 + h * 16 + col) * FDIM + kg * 8;
    }

    // A-frag row bases (element offsets before swizzle)
    int rbase[4];
#pragma unroll
    for (int m = 0; m < 4; ++m) rbase[m] = (m * 16 + col) * FDIM + kg * 8;
    const int amask = col << 3;   // (r&15)<<3 with r = m*16+col

#pragma unroll 1
    for (int ks = 0; ks < 16; ++ks) {
        bf16x8 a[4];
#pragma unroll
        for (int m = 0; m < 4; ++m)
            a[m] = *(const bf16x8*)(xs + ((rbase[m] + ks * 32) ^ amask));

        if (ks <= p0) {
#pragma unroll
            for (int h = 0; h < 2; ++h) {
                bf16x8 b = *(const bf16x8*)(qp[0][h] + ks * 32);
#pragma unroll
                for (int m = 0; m < 4; ++m)
                    acc[0][h][m] = __builtin_amdgcn_mfma_f32_16x16x32_bf16(a[m], b, acc[0][h][m], 0, 0, 0);
            }
        }
        if (ks <= p1) {
#pragma unroll
            for (int h = 0; h < 2; ++h) {
                bf16x8 b = *(const bf16x8*)(qp[1][h] + ks * 32);
#pragma unroll
                for (int m = 0; m < 4; ++m)
                    acc[1][h][m] = __builtin_amdgcn_mfma_f32_16x16x32_bf16(a[m], b, acc[1][h][m], 0, 0, 0);
            }
        }
    }

    // ---- epilogue: rs += xQ_frag * x  (D: col = lane&15, row = kg*4 + j) ----
    float rs[4][4];
#pragma unroll
    for (int m = 0; m < 4; ++m)
#pragma unroll
        for (int j = 0; j < 4; ++j) rs[m][j] = 0.0f;

#pragma unroll
    for (int pi = 0; pi < 2; ++pi) {
        const int p = pi ? p1 : p0;
#pragma unroll
        for (int h = 0; h < 2; ++h) {
            const int c0 = p * 32 + h * 16;
#pragma unroll
            for (int m = 0; m < 4; ++m) {
#pragma unroll
                for (int j = 0; j < 4; ++j) {
                    int r = m * 16 + kg * 4 + j;
                    int e = (r * FDIM + c0 + col) ^ ((r & 15) << 3);
                    rs[m][j] += acc[pi][h][m][j] * (float)xs[e];
                }
            }
        }
    }

    // ---- reduce across 16 cols (lanes sharing kg) ----
#pragma unroll
    for (int m = 0; m < 4; ++m) {
#pragma unroll
        for (int j = 0; j < 4; ++j) {
            float v2 = rs[m][j];
            v2 += __shfl_xor(v2, 1);
            v2 += __shfl_xor(v2, 2);
            v2 += __shfl_xor(v2, 4);
            v2 += __shfl_xor(v2, 8);
            rs[m][j] = v2;
        }
    }
    if (col == 0) {
#pragma unroll
        for (int m = 0; m < 4; ++m)
#pragma unroll
            for (int j = 0; j < 4; ++j)
                rsum[w][m * 16 + kg * 4 + j] = rs[m][j];
    }
    __syncthreads();

    if (tid < BM) {
        float s = 0.0f;
#pragma unroll
        for (int ww = 0; ww < 8; ++ww) s += rsum[ww][tid];
        out[blk + tid] = s;
    }
}

extern "C" void kernel_launch(void* const* d_in, const int* in_sizes, int n_in,
                              void* d_out, int out_size, void* d_ws, size_t ws_size,
                              hipStream_t stream) {
    const float* x = (const float*)d_in[0];
    const float* Q = (const float*)d_in[1];
    float* out = (float*)d_out;
    bf16_t* Qt = (bf16_t*)d_ws;        // 512*512*2 = 512 KB scratch

    const int B = in_sizes[0] / FDIM;  // 131072

    dim3 tgrid(FDIM / 32, FDIM / 32);
    qtrans_kernel<<<tgrid, 256, 0, stream>>>(Q, Qt);
    bilinear_kernel<<<B / BM, NTHR, 0, stream>>>(x, Qt, out);
}